// Round 1
// baseline (321.883 us; speedup 1.0000x reference)
//
#include <hip/hip_runtime.h>

// Problem constants (from reference):
//   EMB_SHAPE = (128, 128, 2048), N_CLASSES = 8, TAU = 0.3, B = 2
//   out[b,k,:] = (mean_n(prob[b,n,k]) > TAU) * emb[b, argmax_n(prob[b,n,k]), :]
// Only 16 rows of emb are read -> total traffic ~1.25 MB. One fused kernel,
// one block per (b,k): reduce 16384-elem class column, then gather 2048 floats.

#define HH 128
#define WW 128
#define CC 2048
#define KK 8
#define NPOS (HH * WW)          // 16384
#define TAU_F 0.3f
#define NTHREADS 256

__global__ __launch_bounds__(NTHREADS) void maxfeat_fused_kernel(
    const float* __restrict__ emb,   // [B, N, C]
    const float* __restrict__ prob,  // [B, N, K]
    float* __restrict__ out)         // [B, K, C]
{
    const int bk  = blockIdx.x;      // 0 .. B*K-1
    const int b   = bk / KK;
    const int k   = bk % KK;
    const int tid = threadIdx.x;

    // ---- Stage 1: strided reduction over N positions (argmax + sum) ----
    float best  = -INFINITY;
    int   besti = 0x7fffffff;
    float sum   = 0.0f;
    const float* p = prob + (size_t)b * NPOS * KK + k;
    for (int n = tid; n < NPOS; n += NTHREADS) {
        float v = p[(size_t)n * KK];
        sum += v;
        // n increases monotonically per thread, so '>' alone keeps the
        // first occurrence within a thread; cross-thread ties resolved below.
        if (v > best) { best = v; besti = n; }
    }

    // wave64 reduce (max+argmax with first-occurrence tie-break, and sum)
    #pragma unroll
    for (int off = 32; off > 0; off >>= 1) {
        float ob = __shfl_down(best,  off, 64);
        int   oi = __shfl_down(besti, off, 64);
        float os = __shfl_down(sum,   off, 64);
        sum += os;
        if (ob > best || (ob == best && oi < besti)) { best = ob; besti = oi; }
    }

    // cross-wave reduce via LDS (4 waves)
    __shared__ float s_best[4];
    __shared__ int   s_idx[4];
    __shared__ float s_sum[4];
    __shared__ int   s_final_idx;
    __shared__ float s_scale;

    const int wave = tid >> 6;
    if ((tid & 63) == 0) { s_best[wave] = best; s_idx[wave] = besti; s_sum[wave] = sum; }
    __syncthreads();
    if (tid == 0) {
        best  = s_best[0]; besti = s_idx[0]; sum = s_sum[0];
        #pragma unroll
        for (int wv = 1; wv < 4; ++wv) {
            float ob = s_best[wv]; int oi = s_idx[wv];
            sum += s_sum[wv];
            if (ob > best || (ob == best && oi < besti)) { best = ob; besti = oi; }
        }
        s_final_idx = besti;
        s_scale = (sum * (1.0f / NPOS) > TAU_F) ? 1.0f : 0.0f;
    }
    __syncthreads();
    const int   idx   = s_final_idx;
    const float scale = s_scale;

    // ---- Stage 2: gather one emb row (2048 floats) with float4 loads ----
    const float4* __restrict__ src =
        (const float4*)(emb + ((size_t)b * NPOS + (size_t)idx) * CC);
    float4* __restrict__ dst = (float4*)(out + (size_t)bk * CC);
    #pragma unroll
    for (int i = tid; i < CC / 4; i += NTHREADS) {  // 512 float4s, 2 per thread
        float4 v = src[i];
        v.x *= scale; v.y *= scale; v.z *= scale; v.w *= scale;
        dst[i] = v;
    }
}

extern "C" void kernel_launch(void* const* d_in, const int* in_sizes, int n_in,
                              void* d_out, int out_size, void* d_ws, size_t ws_size,
                              hipStream_t stream) {
    const float* emb  = (const float*)d_in[0];   // [B, H, W, C] fp32
    const float* prob = (const float*)d_in[1];   // [B, H, W, K] fp32
    float* out = (float*)d_out;                  // [B, K, C] fp32

    const int B = in_sizes[0] / (HH * WW * CC);  // = 2
    maxfeat_fused_kernel<<<B * KK, NTHREADS, 0, stream>>>(emb, prob, out);
}